// Round 9
// baseline (485.906 us; speedup 1.0000x reference)
//
#include <hip/hip_runtime.h>

// EventTransformer on MI355X. B=2, N=8192, C=CN=64, M=16, H=180, W=240.
// fp32 internal in d_ws. I/O dtype (fp32/bf16) runtime-detected.
//
// R9: kill register-spill (R8: kC FETCH 150MB/WRITE 272MB = scratch traffic
// from wcol[64] arrays). kC: SW=S@Wsa2 hoisted to kB (16-step combine),
// kg/vg via 32-reg half-columns (2 fills, L1-cached). kA: edge-only direct
// loads, no arrays. Parallel 2-batch layout (fallback sequential) as R8.

typedef unsigned short u16;
typedef unsigned long long ull;

#define NB 8192
#define IMG_H 180
#define IMG_W 240
#define HWPIX (IMG_H*IMG_W)          // 43200
#define SPB (HWPIX*64)               // 2,764,800 floats
#define NC (NB*64)                   // 524,288

// tail-relative offsets (floats), per-batch strides noted
#define TT_AC    0        // +bb*8192
#define TT_T     16384    // +bb*8192
#define TT_W1    32768
#define TT_EDGEV 32960    // +bb*1024
#define TT_EDGEF 35008    // +bb*1024
#define TT_S     37056    // +bb*1024  (holds SW = S@Wsa2)
#define TT_SEL   39104    // +bb*3072
#define TT_CG    45248    // +bb*64
#define TT_ESUM  45376    // +bb*16
#define TT_STATS 45408    // +bb*16
#define TT_SYNC  45440    // +(bb*3+g)*32 ; [par][blk] 2x8 ull
#define TT_GCNT  45632    // +bb*16
#define TT_ZOFF  45376
#define TT_ZCNT  288
#define TT_TOT   45664

__device__ __forceinline__ float bf2f(u16 u){
  union { unsigned int i; float f; } w; w.i = ((unsigned int)u) << 16; return w.f;
}
__device__ __forceinline__ u16 f2bf(float f){
  union { unsigned int i; float f; } w; w.f = f;
  unsigned int x = w.i;
  x += 0x7fffu + ((x >> 16) & 1u);   // RNE
  return (u16)(x >> 16);
}
__device__ __forceinline__ bool isbf(const void* ev){
  unsigned w3 = ((const unsigned*)ev)[3];
  return !(w3 == 0x3F800000u || w3 == 0xBF800000u);
}
__device__ __forceinline__ float ld(const void* p, int i, bool bf){
  return bf ? bf2f(((const u16*)p)[i]) : ((const float*)p)[i];
}
__device__ __forceinline__ void stout(void* o, long i, float v, bool bf){
  if (bf) ((u16*)o)[i] = f2bf(v); else ((float*)o)[i] = v;
}
__device__ __forceinline__ float waveSum(float v){
#pragma unroll
  for (int m = 1; m < 64; m <<= 1) v += __shfl_xor(v, m, 64);
  return v;
}
__device__ __forceinline__ ull waveMaxU64(ull v){
#pragma unroll
  for (int m = 1; m < 64; m <<= 1){
    ull o = (ull)__shfl_xor((long long)v, m, 64);
    if (o > v) v = o;
  }
  return v;
}
// pack: [52:45]=phase, [44:13]=dist bits (d>=0), [12:0]=8191-idx (tie->min idx)
__device__ __forceinline__ ull packPDI(int phase, float d, int n){
  return ((ull)phase << 45) | ((ull)__float_as_uint(d) << 13) | (ull)(8191 - n);
}
__device__ __forceinline__ int unpackI(ull p){ return 8191 - (int)(p & 0x1FFFull); }

// ---- kW: weight precompute + tail zero (runs once)
__global__ void kW(const void* __restrict__ ev, const void* __restrict__ Wq,
                   const void* __restrict__ Wk, const void* __restrict__ Wpe,
                   const void* __restrict__ w1, float* __restrict__ ws, int tail){
  const bool bf = isbf(ev);
  const int tid = threadIdx.x;  // 256
  for (int i = tid; i < TT_ZCNT; i += 256) ws[tail + TT_ZOFF + i] = 0.f;
  if (tid < 64){
    float s1 = 0.f, s2 = 0.f;
    for (int c = 0; c < 64; c++){
      float wc = ld(w1, c, bf);
      s1 += ld(Wq, tid*64 + c, bf) * wc;
      s2 += ld(Wk, tid*64 + c, bf) * wc;
    }
    ws[tail + TT_W1 + tid] = s1;
    ws[tail + TT_W1 + 64 + tid] = s2;
    if (tid < 4){
      float s3 = 0.f;
      for (int c = 0; c < 64; c++) s3 += ld(Wpe, tid*64 + c, bf) * ld(w1, c, bf);
      ws[tail + TT_W1 + 128 + tid] = s3;
    }
  }
}

// ---- kE: ESUM[bb][i] = sum_n events[bb,n,i]
__global__ void __launch_bounds__(256) kE(const void* __restrict__ ev,
    float* __restrict__ ws, int tail, int bb0){
  const bool bf = isbf(ev);
  const int bb = bb0 + blockIdx.z;
  const int lane = threadIdx.x & 63, w = threadIdx.x >> 6;
  float s0 = 0.f, s1 = 0.f, s2 = 0.f, s3 = 0.f;
#pragma unroll
  for (int j = 0; j < 4; j++){
    int r = blockIdx.x*256 + threadIdx.x + 2048*j;
    const int e4 = (bb*NB + r)*4;
    s0 += ld(ev, e4+0, bf); s1 += ld(ev, e4+1, bf);
    s2 += ld(ev, e4+2, bf); s3 += ld(ev, e4+3, bf);
  }
  s0 = waveSum(s0); s1 = waveSum(s1); s2 = waveSum(s2); s3 = waveSum(s3);
  __shared__ float r4[4][4];
  if (lane == 0){ r4[w][0]=s0; r4[w][1]=s1; r4[w][2]=s2; r4[w][3]=s3; }
  __syncthreads();
  if (threadIdx.x < 4)
    atomicAdd(&ws[tail + TT_ESUM + bb*16 + threadIdx.x],
              r4[0][threadIdx.x]+r4[1][threadIdx.x]+r4[2][threadIdx.x]+r4[3][threadIdx.x]);
}

// ---- kA: 1024 blocks/batch, 8 rows each. No big arrays (spill-free).
__global__ void __launch_bounds__(256, 4) kA(const void* __restrict__ ev,
    const void* __restrict__ Wm, const void* __restrict__ Wpe,
    const void* __restrict__ Wv, float* __restrict__ ws,
    int offA, int strA, int tail, int bb0){
  const bool bf = isbf(ev);
  const int bb = bb0 + blockIdx.z;
  const int lane = threadIdx.x & 63, w = threadIdx.x >> 6;
  float* A = ws + offA + (size_t)bb*strA;
  const float wq1 = ws[tail + TT_W1 + lane];
  const float wk1 = ws[tail + TT_W1 + 64 + lane];
  const float wp10 = ws[tail+TT_W1+128], wp11 = ws[tail+TT_W1+129],
              wp12 = ws[tail+TT_W1+130], wp13 = ws[tail+TT_W1+131];
  const float wm0 = ld(Wm, 0*64+lane, bf), wm1 = ld(Wm, 1*64+lane, bf),
              wm2 = ld(Wm, 2*64+lane, bf), wm3 = ld(Wm, 3*64+lane, bf);
  const bool edgeBlk = (blockIdx.x == 0 || blockIdx.x == 1023);
#pragma unroll
  for (int i = 0; i < 2; i++){
    const int n = blockIdx.x*8 + w + 4*i;
    const int e4 = (bb*NB + n)*4;
    float e0 = ld(ev, e4+0, bf), e1 = ld(ev, e4+1, bf),
          e2 = ld(ev, e4+2, bf), e3 = ld(ev, e4+3, bf);
    float lx = e0*wm0 + e1*wm1 + e2*wm2 + e3*wm3;
    float epe = e0*wp10 + e1*wp11 + e2*wp12 + e3*wp13;
    float acv = waveSum(lx * wq1) + epe;
    float tv  = waveSum(lx * wk1) + epe;
    A[n*64 + lane] = lx;
    if (lane == 0){
      ws[tail + TT_AC + bb*8192 + n] = acv;
      ws[tail + TT_T  + bb*8192 + n] = tv;
    }
    if (edgeBlk && (n < 8 || n >= NB-8)){
      int e = (n < 8) ? n : (n - (NB-16));
      float v = 0.f;
      for (int cn = 0; cn < 64; cn++)
        v += __shfl(lx, cn, 64) * ld(Wv, cn*64 + lane, bf);
      float f = e0*ld(Wpe, lane, bf) + e1*ld(Wpe, 64+lane, bf)
              + e2*ld(Wpe, 128+lane, bf) + e3*ld(Wpe, 192+lane, bf);
      ws[tail + TT_EDGEV + bb*1024 + e*64 + lane] = v;
      ws[tail + TT_EDGEF + bb*1024 + e*64 + lane] = f;
    }
  }
}

// ---- kB: VSUM from ESUM algebra; S[m,c]; then SW[m] = S[m]@Wsa2 (hoisted)
__global__ void __launch_bounds__(64) kB(const void* __restrict__ ev,
    const void* __restrict__ Wm, const void* __restrict__ Wv,
    const void* __restrict__ Wsa2, float* __restrict__ ws, int tail, int bb0){
  const bool bf = isbf(ev);
  const int bb = bb0 + blockIdx.z;
  const int m = blockIdx.x, lane = threadIdx.x;
  float tm = 0.f;
#pragma unroll
  for (int i = 0; i < 4; i++) tm += ws[tail + TT_ESUM + bb*16 + i] * ld(Wm, i*64 + lane, bf);
  float vs0 = 0.f, vs1 = 0.f;
#pragma unroll
  for (int j = 0; j < 64; j += 2){
    vs0 += __shfl(tm, j, 64)   * ld(Wv, j*64 + lane, bf);
    vs1 += __shfl(tm, j+1, 64) * ld(Wv, (j+1)*64 + lane, bf);
  }
  float vsum = vs0 + vs1;
  const int d = m - 8;
  float sv = 0.f, sf = 0.f;
  const float* EV = ws + tail + TT_EDGEV + bb*1024;
  const float* EF = ws + tail + TT_EDGEF + bb*1024;
  if (d < 0){
    for (int e = 16 + d; e < 16; e++){ sv += EV[e*64+lane]; sf += EF[e*64+lane]; }
  } else {
    for (int e = 0; e < d; e++){ sv += EV[e*64+lane]; sf += EF[e*64+lane]; }
  }
  float S = vsum - sv + sf;
  float sw0 = 0.f, sw1 = 0.f;
#pragma unroll
  for (int c = 0; c < 64; c += 2){
    sw0 += __shfl(S, c, 64)   * ld(Wsa2, c*64 + lane, bf);
    sw1 += __shfl(S, c+1, 64) * ld(Wsa2, (c+1)*64 + lane, bf);
  }
  ws[tail + TT_S + bb*1024 + m*64 + lane] = sw0 + sw1;
}

// ---- kC: softmax + lx_out (via SW) + kg/vg (32-reg half-columns) + LXP
__global__ void __launch_bounds__(256, 4) kC(const void* __restrict__ ev,
    const void* __restrict__ gWk, const void* __restrict__ gWv,
    float* __restrict__ ws,
    int offA, int strA, int offB, int strB, int offC, int strC,
    int offLXP, int strLXP, int tail, int bb0){
  const bool bf = isbf(ev);
  const int bb = bb0 + blockIdx.z;
  float* A = ws + offA + (size_t)bb*strA;
  float* Bp = ws + offB + (size_t)bb*strB;
  float* Cp = ws + offC + (size_t)bb*strC;
  __shared__ float SW_lds[1024];
  __shared__ float lred[4][64];
  const int tid = threadIdx.x, lane = tid & 63, w = tid >> 6;
  for (int i = tid; i < 1024; i += 256) SW_lds[i] = ws[tail + TT_S + bb*1024 + i];
  __syncthreads();
  float lxoR[2];
  float lxsum = 0.f;
#pragma unroll
  for (int i = 0; i < 2; i++){
    const int n = blockIdx.x*8 + w + 4*i;
    float lx  = A[n*64 + lane];
    float acn = ws[tail + TT_AC + bb*8192 + n];
    const int m = lane & 15;
    const int j = n + m - 8;
    float tv = (j >= 0 && j < NB) ? ws[tail + TT_T + bb*8192 + j] : 0.f;
    float logit = acn - tv;
    float mx = logit;
#pragma unroll
    for (int k = 1; k < 16; k <<= 1) mx = fmaxf(mx, __shfl_xor(mx, k, 64));
    float ex = expf(logit - mx);
    float sm = ex;
#pragma unroll
    for (int k = 1; k < 16; k <<= 1) sm += __shfl_xor(sm, k, 64);
    float sig = ex / sm;
    float sa = 0.f;
#pragma unroll
    for (int mm = 0; mm < 16; mm++) sa += __shfl(sig, mm, 64) * SW_lds[mm*64 + lane];
    float lxo = lx + sa;
    lxoR[i] = lxo;
    Bp[n*64 + lane] = lxo;
    lxsum += lxo;
  }
  lred[w][lane] = lxsum;
  // kg = lxo @ gWk via 32-reg half-columns (2 fills, L1-cached weights)
  {
    float a0 = 0.f, a1 = 0.f;
    float wc[32];
#pragma unroll
    for (int h = 0; h < 2; h++){
#pragma unroll
      for (int jj = 0; jj < 32; jj++) wc[jj] = ld(gWk, (h*32+jj)*64 + lane, bf);
#pragma unroll
      for (int jj = 0; jj < 32; jj++){
        const int cn = h*32 + jj;
        a0 += __shfl(lxoR[0], cn, 64) * wc[jj];
        a1 += __shfl(lxoR[1], cn, 64) * wc[jj];
      }
    }
    A[(blockIdx.x*8 + w)*64 + lane] = a0;
    A[(blockIdx.x*8 + w + 4)*64 + lane] = a1;
  }
  // vg = lxo @ gWv
  {
    float a0 = 0.f, a1 = 0.f;
    float wc[32];
#pragma unroll
    for (int h = 0; h < 2; h++){
#pragma unroll
      for (int jj = 0; jj < 32; jj++) wc[jj] = ld(gWv, (h*32+jj)*64 + lane, bf);
#pragma unroll
      for (int jj = 0; jj < 32; jj++){
        const int cn = h*32 + jj;
        a0 += __shfl(lxoR[0], cn, 64) * wc[jj];
        a1 += __shfl(lxoR[1], cn, 64) * wc[jj];
      }
    }
    Cp[(blockIdx.x*8 + w)*64 + lane] = a0;
    Cp[(blockIdx.x*8 + w + 4)*64 + lane] = a1;
  }
  __syncthreads();
  if (tid < 64)
    ws[offLXP + (size_t)bb*strLXP + blockIdx.x*64 + tid] =
      lred[0][tid]+lred[1][tid]+lred[2][tid]+lred[3][tid];
}

// ---- kFPS: grid (8,3,nb). Leaderless single-cacheline slot barrier.
__global__ void __launch_bounds__(512) kFPS(const void* __restrict__ ev,
    const void* __restrict__ gWk, const void* __restrict__ gWv,
    const void* __restrict__ gWpe, const void* __restrict__ gWsa1,
    const void* __restrict__ gWsa2, float* __restrict__ ws,
    int offA, int strA, int offB, int strB, int offC, int strC,
    int offLXP, int strLXP, int tail, int bb0){
  const int g = blockIdx.y, idx = blockIdx.x;
  const int bb = bb0 + blockIdx.z;
  const int tid = threadIdx.x, lane = tid & 63, w = tid >> 6;
  const float* pts = ws + (g == 0 ? offB + (size_t)bb*strB
                         : g == 1 ? offA + (size_t)bb*strA
                                  : offC + (size_t)bb*strC);
  ull* slot = (ull*)(ws + tail + TT_SYNC + (bb*3 + g)*32);  // [par*8+blk]
  int* gcnt = (int*)(ws + tail + TT_GCNT + bb*16);

  __shared__ float cent[64];
  __shared__ float red[8][64];
  __shared__ float lxsS[64];
  __shared__ ull   wvS[8];
  __shared__ int   selS[16];
  __shared__ int   sCur;
  __shared__ float gfS[1024];
  __shared__ float betaS[16];
  __shared__ float GS[64];

  const int n0 = idx*1024 + tid;       // +0 and +512
  float4 P[2][16];
#pragma unroll
  for (int j = 0; j < 2; j++)
#pragma unroll
    for (int i = 0; i < 16; i++)
      P[j][i] = ((const float4*)(pts + (size_t)(n0 + j*512)*64))[i];

  // head: LXSUM from 1024 partials; cent analytically per group
  {
    const int c = tid & 63, grp = tid >> 6;
    float s = 0.f;
    const float* LXP = ws + offLXP + (size_t)bb*strLXP;
    for (int b2 = grp; b2 < 1024; b2 += 8) s += LXP[b2*64 + c];
    red[grp][c] = s;
  }
  __syncthreads();
  const bool bf = isbf(ev);
  if (tid < 64){
    float lxs = 0.f;
#pragma unroll
    for (int q = 0; q < 8; q++) lxs += red[q][tid];
    lxsS[tid] = lxs;
    float c;
    if (g == 0) c = lxs * (1.0f/NB);
    else {
      const void* W = (g == 1) ? gWk : gWv;
      float s = 0.f;
#pragma unroll
      for (int j = 0; j < 64; j++) s += __shfl(lxs, j, 64) * ld(W, j*64 + tid, bf);
      c = s * (1.0f/NB);
    }
    cent[tid] = c;
  }
  __syncthreads();

  const float4* cv = (const float4*)cent;
  float md[2] = {1e10f, 1e10f};
  int cur;

  // phase 1: farthest0 (dist to bary, no md update)
  {
    float dd[2];
#pragma unroll
    for (int j = 0; j < 2; j++){
      float d = 0.f;
#pragma unroll
      for (int i = 0; i < 16; i++){
        float4 c = cv[i];
        float dx = P[j][i].x-c.x, dy = P[j][i].y-c.y, dz = P[j][i].z-c.z, dw = P[j][i].w-c.w;
        d += dx*dx; d += dy*dy; d += dz*dz; d += dw*dw;
      }
      dd[j] = d;
    }
    ull p0 = packPDI(1, dd[0], n0);
    ull p1 = packPDI(1, dd[1], n0 + 512);
    ull bp = waveMaxU64(p0 > p1 ? p0 : p1);
    if (lane == 0) wvS[w] = bp;
    __syncthreads();
    if (w == 0){
      ull v = (lane < 8) ? wvS[lane] : 0;
#pragma unroll
      for (int m = 1; m < 8; m <<= 1){
        ull o = (ull)__shfl_xor((long long)v, m, 64);
        if (o > v) v = o;
      }
      if (lane == 0)
        __hip_atomic_store(&slot[8 + idx], v, __ATOMIC_RELEASE, __HIP_MEMORY_SCOPE_AGENT);
      ull got;
      for (;;){
        got = (lane < 8) ? __hip_atomic_load(&slot[8 + lane], __ATOMIC_RELAXED, __HIP_MEMORY_SCOPE_AGENT) : 0;
        ull ok = __ballot(lane >= 8 || (int)(got >> 45) == 1);
        if (ok == ~0ull) break;
        __builtin_amdgcn_s_sleep(1);
      }
#pragma unroll
      for (int m = 1; m < 8; m <<= 1){
        ull o = (ull)__shfl_xor((long long)got, m, 64);
        if (o > got) got = o;
      }
      if (lane == 0) sCur = unpackI(got);
    }
    __syncthreads();
    cur = sCur;
  }

  for (int it = 0; ; it++){
    if (tid == 0) selS[it] = cur;
    if (it == 15) break;
    if (tid < 16) ((float4*)cent)[tid] = ((const float4*)(pts + (size_t)cur*64))[tid];
    __syncthreads();
    const int phase = it + 2;
    float dd[2];
#pragma unroll
    for (int j = 0; j < 2; j++){
      float d = 0.f;
#pragma unroll
      for (int i = 0; i < 16; i++){
        float4 c = cv[i];
        float dx = P[j][i].x-c.x, dy = P[j][i].y-c.y, dz = P[j][i].z-c.z, dw = P[j][i].w-c.w;
        d += dx*dx; d += dy*dy; d += dz*dz; d += dw*dw;
      }
      md[j] = fminf(md[j], d);
      dd[j] = md[j];
    }
    ull p0 = packPDI(phase, dd[0], n0);
    ull p1 = packPDI(phase, dd[1], n0 + 512);
    ull bp = waveMaxU64(p0 > p1 ? p0 : p1);
    if (lane == 0) wvS[w] = bp;
    __syncthreads();
    const int par = phase & 1;
    if (w == 0){
      ull v = (lane < 8) ? wvS[lane] : 0;
#pragma unroll
      for (int m = 1; m < 8; m <<= 1){
        ull o = (ull)__shfl_xor((long long)v, m, 64);
        if (o > v) v = o;
      }
      if (lane == 0)
        __hip_atomic_store(&slot[par*8 + idx], v, __ATOMIC_RELEASE, __HIP_MEMORY_SCOPE_AGENT);
      ull got;
      for (;;){
        got = (lane < 8) ? __hip_atomic_load(&slot[par*8 + lane], __ATOMIC_RELAXED, __HIP_MEMORY_SCOPE_AGENT) : 0;
        ull ok = __ballot(lane >= 8 || (int)(got >> 45) == phase);
        if (ok == ~0ull) break;
        __builtin_amdgcn_s_sleep(1);
      }
#pragma unroll
      for (int m = 1; m < 8; m <<= 1){
        ull o = (ull)__shfl_xor((long long)got, m, 64);
        if (o > got) got = o;
      }
      if (lane == 0) sCur = unpackI(got);
    }
    __syncthreads();
    cur = sCur;
  }
  __syncthreads();

  if (idx == 0){
    if (tid == 0){
      for (int i = 1; i < 16; i++){
        int key = selS[i]; int j = i - 1;
        while (j >= 0 && selS[j] > key){ selS[j+1] = selS[j]; j--; }
        selS[j+1] = key;
      }
    }
    __syncthreads();
    for (int idx2 = tid; idx2 < 1024; idx2 += 512)
      ws[tail + TT_SEL + bb*3072 + g*1024 + idx2] = pts[(size_t)selS[idx2 >> 6]*64 + (idx2 & 63)];
    __threadfence();
  }
  __syncthreads();
  if (tid == 0) atomicAdd(gcnt, 1);
  if (g != 0 || idx != 0) return;

  // ---- kG tail (per batch)
  if (tid == 0){
    while (__hip_atomic_load(gcnt, __ATOMIC_RELAXED, __HIP_MEMORY_SCOPE_AGENT) < 24)
      __builtin_amdgcn_s_sleep(1);
    __threadfence();
  }
  __syncthreads();
  if (tid < 64){
    const float gw1 = ld(gWsa1, tid, bf);
    float G = 0.f;
    {
      float lxs = lxsS[tid];
#pragma unroll
      for (int cn = 0; cn < 64; cn++) G += __shfl(lxs, cn, 64) * ld(gWpe, cn*64 + tid, bf);
    }
    GS[tid] = G;
    const float* selp = ws + tail + TT_SEL + bb*3072;
    for (int m = 0; m < 16; m++){
      float plx = selp[m*64 + tid];
      float g2 = 0.f;
#pragma unroll
      for (int cn = 0; cn < 64; cn++) g2 += __shfl(plx, cn, 64) * ld(gWpe, cn*64 + tid, bf);
      gfS[m*64 + tid] = g2;
      float pkv = selp[1024 + m*64 + tid];
      float part = waveSum((pkv + g2) * gw1);
      if (tid == 0) betaS[m] = part;
    }
  }
  __syncthreads();
  if (tid < 64){
    float mx = -1e30f;
    for (int m = 0; m < 16; m++) mx = fmaxf(mx, -betaS[m]);
    float ssum = 0.f;
    for (int m = 0; m < 16; m++) ssum += expf(-betaS[m] - mx);
    float A = 0.f;
    for (int m = 0; m < 16; m++){
      float sg = expf(-betaS[m] - mx) / ssum;
      float pv = ws[tail + TT_SEL + bb*3072 + 2048 + m*64 + tid];
      float Sg = 8192.0f * (pv - gfS[m*64 + tid]) + GS[tid];
      A += sg * Sg;
    }
    float cg = 0.f;
#pragma unroll
    for (int cn = 0; cn < 64; cn++) cg += __shfl(A, cn, 64) * ld(gWsa2, cn*64 + tid, bf);
    ws[tail + TT_CG + bb*64 + tid] = cg;
  }
}

// ---- kZeroSpace: grid (2700,1,nb)
__global__ void kZeroSpace(float* __restrict__ ws, int offSp, int strSp, int bb0){
  const int bb = bb0 + blockIdx.z;
  float4 z = make_float4(0.f, 0.f, 0.f, 0.f);
  ((float4*)(ws + offSp + (size_t)bb*strSp))[blockIdx.x*256 + threadIdx.x] = z;
}

// ---- kImg: LN + GELU + scatter-add
__global__ void __launch_bounds__(256, 4) kImg(const void* __restrict__ ev,
    const void* __restrict__ lnw, const void* __restrict__ lnb,
    float* __restrict__ ws, int offB, int strB, int offSp, int strSp,
    int tail, int bb0){
  const bool bf = isbf(ev);
  const int bb = bb0 + blockIdx.z;
  const int lane = threadIdx.x & 63, w = threadIdx.x >> 6;
  const float cg = ws[tail + TT_CG + bb*64 + lane];
  const float lw = ld(lnw, lane, bf), lb = ld(lnb, lane, bf);
  float* space = ws + offSp + (size_t)bb*strSp;
  const float* Bp = ws + offB + (size_t)bb*strB;
#pragma unroll
  for (int i = 0; i < 2; i++){
    const int n = blockIdx.x*8 + w + 4*i;
    float x = Bp[n*64 + lane] + cg;
    float mu = waveSum(x) * (1.0f/64.0f);
    float dv = x - mu;
    float var = waveSum(dv*dv) * (1.0f/64.0f);
    float xn = dv / sqrtf(var + 1e-5f);
    float y = xn * lw + lb;
    float h = 0.5f * y * (1.0f + erff(y * 0.70710678118654752f));
    const int e4 = (bb*NB + n)*4;
    float exf = ld(ev, e4+0, bf), eyf = ld(ev, e4+1, bf), epf = ld(ev, e4+3, bf);
    int xi = (int)floorf(exf), yi = (int)floorf(eyf);
    int flat = yi*IMG_W + xi;
    flat = max(0, min(HWPIX-1, flat));
    atomicAdd(space + flat*64 + lane, epf * h);
  }
}

// ---- kStat: cnt,sum,sumsq per batch
__global__ void __launch_bounds__(256) kStat(float* __restrict__ ws,
    int offSp, int strSp, int tail, int bb0){
  const int bb = bb0 + blockIdx.z;
  const float4* sp = (const float4*)(ws + offSp + (size_t)bb*strSp);
  float cnt = 0.f, sum = 0.f, ssq = 0.f;
  for (unsigned i = blockIdx.x*256u + threadIdx.x; i < SPB/4; i += 65536u){
    float4 v = sp[i];
    if (v.x != 0.f){ cnt += 1.f; sum += v.x; ssq += v.x*v.x; }
    if (v.y != 0.f){ cnt += 1.f; sum += v.y; ssq += v.y*v.y; }
    if (v.z != 0.f){ cnt += 1.f; sum += v.z; ssq += v.z*v.z; }
    if (v.w != 0.f){ cnt += 1.f; sum += v.w; ssq += v.w*v.w; }
  }
  cnt = waveSum(cnt); sum = waveSum(sum); ssq = waveSum(ssq);
  __shared__ float rc[4], rs[4], rq[4];
  const int lane = threadIdx.x & 63, w = threadIdx.x >> 6;
  if (lane == 0){ rc[w] = cnt; rs[w] = sum; rq[w] = ssq; }
  __syncthreads();
  if (threadIdx.x == 0){
    atomicAdd(&ws[tail + TT_STATS + bb*16 + 0], rc[0]+rc[1]+rc[2]+rc[3]);
    atomicAdd(&ws[tail + TT_STATS + bb*16 + 1], rs[0]+rs[1]+rs[2]+rs[3]);
    atomicAdd(&ws[tail + TT_STATS + bb*16 + 2], rq[0]+rq[1]+rq[2]+rq[3]);
  }
}

// ---- kOut: LDS-transpose 64hw x 64c; var from sum/sumsq
__global__ void __launch_bounds__(256) kOut(const void* __restrict__ ev,
    const float* __restrict__ ws, void* __restrict__ out,
    int offSp, int strSp, int tail, int bb0){
  const bool bf = isbf(ev);
  const int bb = bb0 + blockIdx.z;
  __shared__ float tile[64*64];
  const int tid = threadIdx.x;
  const int hw0 = blockIdx.x*64;
  const float* sp = ws + offSp + (size_t)bb*strSp;
#pragma unroll
  for (int i = 0; i < 16; i++){
    int idx = tid + 256*i;
    tile[idx] = sp[(size_t)hw0*64 + idx];
  }
  const float cnt = ws[tail + TT_STATS + bb*16 + 0];
  const float sum = ws[tail + TT_STATS + bb*16 + 1];
  const float ssq = ws[tail + TT_STATS + bb*16 + 2];
  const float mean = sum / fmaxf(cnt, 1.f);
  const float m2   = fmaxf(ssq - sum*mean, 0.f);
  const float var  = m2 / fmaxf(cnt - 1.f, 1.f);
  const float stdv = sqrtf(var);
  __syncthreads();
  const int c = tid >> 2, sub = tid & 3;
#pragma unroll
  for (int j = 0; j < 16; j++){
    int hwl = sub*16 + j;
    float x = tile[hwl*64 + c];
    float centered = (x != 0.f) ? (x - mean) : x;
    float normed = (stdv > 0.f) ? (centered / stdv) : centered;
    float o = (cnt > 0.f) ? normed : x;
    stout(out, (long)(bb*64 + c)*HWPIX + hw0 + hwl, o, bf);
  }
}

extern "C" void kernel_launch(void* const* d_in, const int* in_sizes, int n_in,
                              void* d_out, int out_size, void* d_ws, size_t ws_size,
                              hipStream_t stream){
  (void)in_sizes; (void)n_in; (void)out_size;
  const void* ev     = d_in[0];
  const void* Wm     = d_in[1];
  const void* Wpe    = d_in[2];
  const void* lnw    = d_in[3];
  const void* lnb    = d_in[4];
  const void* lxWq   = d_in[5];
  const void* lxWk   = d_in[6];
  const void* lxWv   = d_in[7];
  const void* lxWsa1 = d_in[8];
  const void* lxWsa2 = d_in[9];
  // d_in[10] = gx_Wq : unused (cancels in n-independent softmax)
  const void* gxWk   = d_in[11];
  const void* gxWv   = d_in[12];
  const void* gxWpe  = d_in[13];
  const void* gxWsa1 = d_in[14];
  const void* gxWsa2 = d_in[15];
  float* ws = (float*)d_ws;

  // Parallel layout: B[2NC] | SPACE[2SPB] (aliases A,C,LXP) | tail
  const int P_TAIL = 2*NC + 2*SPB;
  const size_t PAR_BYTES = (size_t)(P_TAIL + TT_TOT) * 4;
  const bool par = ws_size >= PAR_BYTES;

  int offB, strB, offSp, strSp, offA, strA, offC, strC, offLXP, strLXP, tail;
  if (par){
    offB = 0;        strB = NC;
    offSp = 2*NC;    strSp = SPB;
    offA = 2*NC;     strA = NC;
    offC = 4*NC;     strC = NC;
    offLXP = 6*NC;   strLXP = 65536;
    tail = P_TAIL;
  } else {
    offSp = 0;       strSp = 0;
    offA = 0;        strA = 0;
    offC = NC;       strC = 0;
    offLXP = 2*NC;   strLXP = 0;
    offB = SPB;      strB = 0;
    tail = SPB + NC;
  }
  const int nb = par ? 2 : 1;
  const int iters = par ? 1 : 2;

  kW<<<1, 256, 0, stream>>>(ev, lxWq, lxWk, Wpe, lxWsa1, ws, tail);
  for (int t = 0; t < iters; t++){
    const int bb0 = par ? 0 : t;
    kE<<<dim3(8,1,nb), 256, 0, stream>>>(ev, ws, tail, bb0);
    kA<<<dim3(1024,1,nb), 256, 0, stream>>>(ev, Wm, Wpe, lxWv, ws, offA, strA, tail, bb0);
    kB<<<dim3(16,1,nb), 64, 0, stream>>>(ev, Wm, lxWv, lxWsa2, ws, tail, bb0);
    kC<<<dim3(1024,1,nb), 256, 0, stream>>>(ev, gxWk, gxWv, ws,
        offA, strA, offB, strB, offC, strC, offLXP, strLXP, tail, bb0);
    kFPS<<<dim3(8,3,nb), 512, 0, stream>>>(ev, gxWk, gxWv, gxWpe, gxWsa1, gxWsa2, ws,
        offA, strA, offB, strB, offC, strC, offLXP, strLXP, tail, bb0);
    kZeroSpace<<<dim3(2700,1,nb), 256, 0, stream>>>(ws, offSp, strSp, bb0);
    kImg<<<dim3(1024,1,nb), 256, 0, stream>>>(ev, lnw, lnb, ws, offB, strB, offSp, strSp, tail, bb0);
    kStat<<<dim3(256,1,nb), 256, 0, stream>>>(ws, offSp, strSp, tail, bb0);
    kOut<<<dim3(675,1,nb), 256, 0, stream>>>(ev, ws, d_out, offSp, strSp, tail, bb0);
  }
}

// Round 10
// 426.441 us; speedup vs baseline: 1.1394x; 1.1394x over previous
//
#include <hip/hip_runtime.h>

// EventTransformer on MI355X. B=2, N=8192, C=CN=64, M=16, H=180, W=240.
// fp32 internal in d_ws. I/O dtype (fp32/bf16) runtime-detected.
//
// R10: fix R9 kFPS regression — (a) restore wpec[64] reg array in kG tail
// (R9 removed it -> ~1100 serialized LLC loads on the critical tail, +70us);
// (b) LXP->LXSUM reduction hoisted to tiny kL (48 blocks each re-reduced
// 256KB in R9's kFPS head). kC/kA spill-free as R9 (that fix held).

typedef unsigned short u16;
typedef unsigned long long ull;

#define NB 8192
#define IMG_H 180
#define IMG_W 240
#define HWPIX (IMG_H*IMG_W)          // 43200
#define SPB (HWPIX*64)               // 2,764,800 floats
#define NC (NB*64)                   // 524,288

// tail-relative offsets (floats), per-batch strides noted
#define TT_AC    0        // +bb*8192
#define TT_T     16384    // +bb*8192
#define TT_W1    32768
#define TT_EDGEV 32960    // +bb*1024
#define TT_EDGEF 35008    // +bb*1024
#define TT_S     37056    // +bb*1024  (holds SW = S@Wsa2)
#define TT_SEL   39104    // +bb*3072
#define TT_CG    45248    // +bb*64
#define TT_ESUM  45376    // +bb*16
#define TT_STATS 45408    // +bb*16
#define TT_SYNC  45440    // +(bb*3+g)*32 ; [par][blk] 2x8 ull
#define TT_GCNT  45632    // +bb*16
#define TT_LXS   45664    // +bb*64 (LXSUM, written whole by kL)
#define TT_ZOFF  45376
#define TT_ZCNT  288
#define TT_TOT   45792

__device__ __forceinline__ float bf2f(u16 u){
  union { unsigned int i; float f; } w; w.i = ((unsigned int)u) << 16; return w.f;
}
__device__ __forceinline__ u16 f2bf(float f){
  union { unsigned int i; float f; } w; w.f = f;
  unsigned int x = w.i;
  x += 0x7fffu + ((x >> 16) & 1u);   // RNE
  return (u16)(x >> 16);
}
__device__ __forceinline__ bool isbf(const void* ev){
  unsigned w3 = ((const unsigned*)ev)[3];
  return !(w3 == 0x3F800000u || w3 == 0xBF800000u);
}
__device__ __forceinline__ float ld(const void* p, int i, bool bf){
  return bf ? bf2f(((const u16*)p)[i]) : ((const float*)p)[i];
}
__device__ __forceinline__ void stout(void* o, long i, float v, bool bf){
  if (bf) ((u16*)o)[i] = f2bf(v); else ((float*)o)[i] = v;
}
__device__ __forceinline__ float waveSum(float v){
#pragma unroll
  for (int m = 1; m < 64; m <<= 1) v += __shfl_xor(v, m, 64);
  return v;
}
__device__ __forceinline__ ull waveMaxU64(ull v){
#pragma unroll
  for (int m = 1; m < 64; m <<= 1){
    ull o = (ull)__shfl_xor((long long)v, m, 64);
    if (o > v) v = o;
  }
  return v;
}
// pack: [52:45]=phase, [44:13]=dist bits (d>=0), [12:0]=8191-idx (tie->min idx)
__device__ __forceinline__ ull packPDI(int phase, float d, int n){
  return ((ull)phase << 45) | ((ull)__float_as_uint(d) << 13) | (ull)(8191 - n);
}
__device__ __forceinline__ int unpackI(ull p){ return 8191 - (int)(p & 0x1FFFull); }

// ---- kW: weight precompute + tail zero (runs once)
__global__ void kW(const void* __restrict__ ev, const void* __restrict__ Wq,
                   const void* __restrict__ Wk, const void* __restrict__ Wpe,
                   const void* __restrict__ w1, float* __restrict__ ws, int tail){
  const bool bf = isbf(ev);
  const int tid = threadIdx.x;  // 256
  for (int i = tid; i < TT_ZCNT; i += 256) ws[tail + TT_ZOFF + i] = 0.f;
  if (tid < 64){
    float s1 = 0.f, s2 = 0.f;
    for (int c = 0; c < 64; c++){
      float wc = ld(w1, c, bf);
      s1 += ld(Wq, tid*64 + c, bf) * wc;
      s2 += ld(Wk, tid*64 + c, bf) * wc;
    }
    ws[tail + TT_W1 + tid] = s1;
    ws[tail + TT_W1 + 64 + tid] = s2;
    if (tid < 4){
      float s3 = 0.f;
      for (int c = 0; c < 64; c++) s3 += ld(Wpe, tid*64 + c, bf) * ld(w1, c, bf);
      ws[tail + TT_W1 + 128 + tid] = s3;
    }
  }
}

// ---- kE: ESUM[bb][i] = sum_n events[bb,n,i]
__global__ void __launch_bounds__(256) kE(const void* __restrict__ ev,
    float* __restrict__ ws, int tail, int bb0){
  const bool bf = isbf(ev);
  const int bb = bb0 + blockIdx.z;
  const int lane = threadIdx.x & 63, w = threadIdx.x >> 6;
  float s0 = 0.f, s1 = 0.f, s2 = 0.f, s3 = 0.f;
#pragma unroll
  for (int j = 0; j < 4; j++){
    int r = blockIdx.x*256 + threadIdx.x + 2048*j;
    const int e4 = (bb*NB + r)*4;
    s0 += ld(ev, e4+0, bf); s1 += ld(ev, e4+1, bf);
    s2 += ld(ev, e4+2, bf); s3 += ld(ev, e4+3, bf);
  }
  s0 = waveSum(s0); s1 = waveSum(s1); s2 = waveSum(s2); s3 = waveSum(s3);
  __shared__ float r4[4][4];
  if (lane == 0){ r4[w][0]=s0; r4[w][1]=s1; r4[w][2]=s2; r4[w][3]=s3; }
  __syncthreads();
  if (threadIdx.x < 4)
    atomicAdd(&ws[tail + TT_ESUM + bb*16 + threadIdx.x],
              r4[0][threadIdx.x]+r4[1][threadIdx.x]+r4[2][threadIdx.x]+r4[3][threadIdx.x]);
}

// ---- kA: 1024 blocks/batch, 8 rows each. Spill-free.
__global__ void __launch_bounds__(256, 4) kA(const void* __restrict__ ev,
    const void* __restrict__ Wm, const void* __restrict__ Wpe,
    const void* __restrict__ Wv, float* __restrict__ ws,
    int offA, int strA, int tail, int bb0){
  const bool bf = isbf(ev);
  const int bb = bb0 + blockIdx.z;
  const int lane = threadIdx.x & 63, w = threadIdx.x >> 6;
  float* A = ws + offA + (size_t)bb*strA;
  const float wq1 = ws[tail + TT_W1 + lane];
  const float wk1 = ws[tail + TT_W1 + 64 + lane];
  const float wp10 = ws[tail+TT_W1+128], wp11 = ws[tail+TT_W1+129],
              wp12 = ws[tail+TT_W1+130], wp13 = ws[tail+TT_W1+131];
  const float wm0 = ld(Wm, 0*64+lane, bf), wm1 = ld(Wm, 1*64+lane, bf),
              wm2 = ld(Wm, 2*64+lane, bf), wm3 = ld(Wm, 3*64+lane, bf);
  const bool edgeBlk = (blockIdx.x == 0 || blockIdx.x == 1023);
#pragma unroll
  for (int i = 0; i < 2; i++){
    const int n = blockIdx.x*8 + w + 4*i;
    const int e4 = (bb*NB + n)*4;
    float e0 = ld(ev, e4+0, bf), e1 = ld(ev, e4+1, bf),
          e2 = ld(ev, e4+2, bf), e3 = ld(ev, e4+3, bf);
    float lx = e0*wm0 + e1*wm1 + e2*wm2 + e3*wm3;
    float epe = e0*wp10 + e1*wp11 + e2*wp12 + e3*wp13;
    float acv = waveSum(lx * wq1) + epe;
    float tv  = waveSum(lx * wk1) + epe;
    A[n*64 + lane] = lx;
    if (lane == 0){
      ws[tail + TT_AC + bb*8192 + n] = acv;
      ws[tail + TT_T  + bb*8192 + n] = tv;
    }
    if (edgeBlk && (n < 8 || n >= NB-8)){
      int e = (n < 8) ? n : (n - (NB-16));
      float v = 0.f;
      for (int cn = 0; cn < 64; cn++)
        v += __shfl(lx, cn, 64) * ld(Wv, cn*64 + lane, bf);
      float f = e0*ld(Wpe, lane, bf) + e1*ld(Wpe, 64+lane, bf)
              + e2*ld(Wpe, 128+lane, bf) + e3*ld(Wpe, 192+lane, bf);
      ws[tail + TT_EDGEV + bb*1024 + e*64 + lane] = v;
      ws[tail + TT_EDGEF + bb*1024 + e*64 + lane] = f;
    }
  }
}

// ---- kB: VSUM from ESUM algebra; S[m,c]; SW[m] = S[m]@Wsa2 (hoisted)
__global__ void __launch_bounds__(64) kB(const void* __restrict__ ev,
    const void* __restrict__ Wm, const void* __restrict__ Wv,
    const void* __restrict__ Wsa2, float* __restrict__ ws, int tail, int bb0){
  const bool bf = isbf(ev);
  const int bb = bb0 + blockIdx.z;
  const int m = blockIdx.x, lane = threadIdx.x;
  float tm = 0.f;
#pragma unroll
  for (int i = 0; i < 4; i++) tm += ws[tail + TT_ESUM + bb*16 + i] * ld(Wm, i*64 + lane, bf);
  float vs0 = 0.f, vs1 = 0.f;
#pragma unroll
  for (int j = 0; j < 64; j += 2){
    vs0 += __shfl(tm, j, 64)   * ld(Wv, j*64 + lane, bf);
    vs1 += __shfl(tm, j+1, 64) * ld(Wv, (j+1)*64 + lane, bf);
  }
  float vsum = vs0 + vs1;
  const int d = m - 8;
  float sv = 0.f, sf = 0.f;
  const float* EV = ws + tail + TT_EDGEV + bb*1024;
  const float* EF = ws + tail + TT_EDGEF + bb*1024;
  if (d < 0){
    for (int e = 16 + d; e < 16; e++){ sv += EV[e*64+lane]; sf += EF[e*64+lane]; }
  } else {
    for (int e = 0; e < d; e++){ sv += EV[e*64+lane]; sf += EF[e*64+lane]; }
  }
  float S = vsum - sv + sf;
  float sw0 = 0.f, sw1 = 0.f;
#pragma unroll
  for (int c = 0; c < 64; c += 2){
    sw0 += __shfl(S, c, 64)   * ld(Wsa2, c*64 + lane, bf);
    sw1 += __shfl(S, c+1, 64) * ld(Wsa2, (c+1)*64 + lane, bf);
  }
  ws[tail + TT_S + bb*1024 + m*64 + lane] = sw0 + sw1;
}

// ---- kC: softmax + lx_out (via SW) + kg/vg (32-reg half-columns) + LXP
__global__ void __launch_bounds__(256, 4) kC(const void* __restrict__ ev,
    const void* __restrict__ gWk, const void* __restrict__ gWv,
    float* __restrict__ ws,
    int offA, int strA, int offB, int strB, int offC, int strC,
    int offLXP, int strLXP, int tail, int bb0){
  const bool bf = isbf(ev);
  const int bb = bb0 + blockIdx.z;
  float* A = ws + offA + (size_t)bb*strA;
  float* Bp = ws + offB + (size_t)bb*strB;
  float* Cp = ws + offC + (size_t)bb*strC;
  __shared__ float SW_lds[1024];
  __shared__ float lred[4][64];
  const int tid = threadIdx.x, lane = tid & 63, w = tid >> 6;
  for (int i = tid; i < 1024; i += 256) SW_lds[i] = ws[tail + TT_S + bb*1024 + i];
  __syncthreads();
  float lxoR[2];
  float lxsum = 0.f;
#pragma unroll
  for (int i = 0; i < 2; i++){
    const int n = blockIdx.x*8 + w + 4*i;
    float lx  = A[n*64 + lane];
    float acn = ws[tail + TT_AC + bb*8192 + n];
    const int m = lane & 15;
    const int j = n + m - 8;
    float tv = (j >= 0 && j < NB) ? ws[tail + TT_T + bb*8192 + j] : 0.f;
    float logit = acn - tv;
    float mx = logit;
#pragma unroll
    for (int k = 1; k < 16; k <<= 1) mx = fmaxf(mx, __shfl_xor(mx, k, 64));
    float ex = expf(logit - mx);
    float sm = ex;
#pragma unroll
    for (int k = 1; k < 16; k <<= 1) sm += __shfl_xor(sm, k, 64);
    float sig = ex / sm;
    float sa = 0.f;
#pragma unroll
    for (int mm = 0; mm < 16; mm++) sa += __shfl(sig, mm, 64) * SW_lds[mm*64 + lane];
    float lxo = lx + sa;
    lxoR[i] = lxo;
    Bp[n*64 + lane] = lxo;
    lxsum += lxo;
  }
  lred[w][lane] = lxsum;
  // kg = lxo @ gWk via 32-reg half-columns
  {
    float a0 = 0.f, a1 = 0.f;
    float wc[32];
#pragma unroll
    for (int h = 0; h < 2; h++){
#pragma unroll
      for (int jj = 0; jj < 32; jj++) wc[jj] = ld(gWk, (h*32+jj)*64 + lane, bf);
#pragma unroll
      for (int jj = 0; jj < 32; jj++){
        const int cn = h*32 + jj;
        a0 += __shfl(lxoR[0], cn, 64) * wc[jj];
        a1 += __shfl(lxoR[1], cn, 64) * wc[jj];
      }
    }
    A[(blockIdx.x*8 + w)*64 + lane] = a0;
    A[(blockIdx.x*8 + w + 4)*64 + lane] = a1;
  }
  // vg = lxo @ gWv
  {
    float a0 = 0.f, a1 = 0.f;
    float wc[32];
#pragma unroll
    for (int h = 0; h < 2; h++){
#pragma unroll
      for (int jj = 0; jj < 32; jj++) wc[jj] = ld(gWv, (h*32+jj)*64 + lane, bf);
#pragma unroll
      for (int jj = 0; jj < 32; jj++){
        const int cn = h*32 + jj;
        a0 += __shfl(lxoR[0], cn, 64) * wc[jj];
        a1 += __shfl(lxoR[1], cn, 64) * wc[jj];
      }
    }
    Cp[(blockIdx.x*8 + w)*64 + lane] = a0;
    Cp[(blockIdx.x*8 + w + 4)*64 + lane] = a1;
  }
  __syncthreads();
  if (tid < 64)
    ws[offLXP + (size_t)bb*strLXP + blockIdx.x*64 + tid] =
      lred[0][tid]+lred[1][tid]+lred[2][tid]+lred[3][tid];
}

// ---- kL: LXP (1024x64) -> LXSUM (64) per batch
__global__ void __launch_bounds__(512) kL(float* __restrict__ ws,
    int offLXP, int strLXP, int tail, int bb0){
  const int bb = bb0 + blockIdx.z;
  __shared__ float red[8][64];
  const int tid = threadIdx.x, c = tid & 63, grp = tid >> 6;
  const float* LXP = ws + offLXP + (size_t)bb*strLXP;
  float s = 0.f;
  for (int b2 = grp; b2 < 1024; b2 += 8) s += LXP[b2*64 + c];
  red[grp][c] = s;
  __syncthreads();
  if (tid < 64){
    float t = 0.f;
#pragma unroll
    for (int q = 0; q < 8; q++) t += red[q][tid];
    ws[tail + TT_LXS + bb*64 + tid] = t;
  }
}

// ---- kFPS: grid (8,3,nb). Leaderless slot barrier; kG tail on block (0,0).
__global__ void __launch_bounds__(512) kFPS(const void* __restrict__ ev,
    const void* __restrict__ gWk, const void* __restrict__ gWv,
    const void* __restrict__ gWpe, const void* __restrict__ gWsa1,
    const void* __restrict__ gWsa2, float* __restrict__ ws,
    int offA, int strA, int offB, int strB, int offC, int strC,
    int tail, int bb0){
  const int g = blockIdx.y, idx = blockIdx.x;
  const int bb = bb0 + blockIdx.z;
  const int tid = threadIdx.x, lane = tid & 63, w = tid >> 6;
  const float* pts = ws + (g == 0 ? offB + (size_t)bb*strB
                         : g == 1 ? offA + (size_t)bb*strA
                                  : offC + (size_t)bb*strC);
  ull* slot = (ull*)(ws + tail + TT_SYNC + (bb*3 + g)*32);  // [par*8+blk]
  int* gcnt = (int*)(ws + tail + TT_GCNT + bb*16);

  __shared__ float cent[64];
  __shared__ float lxsS[64];
  __shared__ ull   wvS[8];
  __shared__ int   selS[16];
  __shared__ int   sCur;
  __shared__ float gfS[1024];
  __shared__ float betaS[16];
  __shared__ float GS[64];

  const int n0 = idx*1024 + tid;       // +0 and +512
  float4 P[2][16];
#pragma unroll
  for (int j = 0; j < 2; j++)
#pragma unroll
    for (int i = 0; i < 16; i++)
      P[j][i] = ((const float4*)(pts + (size_t)(n0 + j*512)*64))[i];

  const bool bf = isbf(ev);
  // head: LXSUM precomputed by kL; cent analytically per group
  if (tid < 64){
    float lxs = ws[tail + TT_LXS + bb*64 + tid];
    lxsS[tid] = lxs;
    float c;
    if (g == 0) c = lxs * (1.0f/NB);
    else {
      const void* W = (g == 1) ? gWk : gWv;
      float s = 0.f;
#pragma unroll
      for (int j = 0; j < 64; j++) s += __shfl(lxs, j, 64) * ld(W, j*64 + tid, bf);
      c = s * (1.0f/NB);
    }
    cent[tid] = c;
  }
  __syncthreads();

  const float4* cv = (const float4*)cent;
  float md[2] = {1e10f, 1e10f};
  int cur;

  // phase 1: farthest0 (dist to bary, no md update)
  {
    float dd[2];
#pragma unroll
    for (int j = 0; j < 2; j++){
      float d = 0.f;
#pragma unroll
      for (int i = 0; i < 16; i++){
        float4 c = cv[i];
        float dx = P[j][i].x-c.x, dy = P[j][i].y-c.y, dz = P[j][i].z-c.z, dw = P[j][i].w-c.w;
        d += dx*dx; d += dy*dy; d += dz*dz; d += dw*dw;
      }
      dd[j] = d;
    }
    ull p0 = packPDI(1, dd[0], n0);
    ull p1 = packPDI(1, dd[1], n0 + 512);
    ull bp = waveMaxU64(p0 > p1 ? p0 : p1);
    if (lane == 0) wvS[w] = bp;
    __syncthreads();
    if (w == 0){
      ull v = (lane < 8) ? wvS[lane] : 0;
#pragma unroll
      for (int m = 1; m < 8; m <<= 1){
        ull o = (ull)__shfl_xor((long long)v, m, 64);
        if (o > v) v = o;
      }
      if (lane == 0)
        __hip_atomic_store(&slot[8 + idx], v, __ATOMIC_RELEASE, __HIP_MEMORY_SCOPE_AGENT);
      ull got;
      for (;;){
        got = (lane < 8) ? __hip_atomic_load(&slot[8 + lane], __ATOMIC_RELAXED, __HIP_MEMORY_SCOPE_AGENT) : 0;
        ull ok = __ballot(lane >= 8 || (int)(got >> 45) == 1);
        if (ok == ~0ull) break;
        __builtin_amdgcn_s_sleep(1);
      }
#pragma unroll
      for (int m = 1; m < 8; m <<= 1){
        ull o = (ull)__shfl_xor((long long)got, m, 64);
        if (o > got) got = o;
      }
      if (lane == 0) sCur = unpackI(got);
    }
    __syncthreads();
    cur = sCur;
  }

  for (int it = 0; ; it++){
    if (tid == 0) selS[it] = cur;
    if (it == 15) break;
    if (tid < 16) ((float4*)cent)[tid] = ((const float4*)(pts + (size_t)cur*64))[tid];
    __syncthreads();
    const int phase = it + 2;
    float dd[2];
#pragma unroll
    for (int j = 0; j < 2; j++){
      float d = 0.f;
#pragma unroll
      for (int i = 0; i < 16; i++){
        float4 c = cv[i];
        float dx = P[j][i].x-c.x, dy = P[j][i].y-c.y, dz = P[j][i].z-c.z, dw = P[j][i].w-c.w;
        d += dx*dx; d += dy*dy; d += dz*dz; d += dw*dw;
      }
      md[j] = fminf(md[j], d);
      dd[j] = md[j];
    }
    ull p0 = packPDI(phase, dd[0], n0);
    ull p1 = packPDI(phase, dd[1], n0 + 512);
    ull bp = waveMaxU64(p0 > p1 ? p0 : p1);
    if (lane == 0) wvS[w] = bp;
    __syncthreads();
    const int par = phase & 1;
    if (w == 0){
      ull v = (lane < 8) ? wvS[lane] : 0;
#pragma unroll
      for (int m = 1; m < 8; m <<= 1){
        ull o = (ull)__shfl_xor((long long)v, m, 64);
        if (o > v) v = o;
      }
      if (lane == 0)
        __hip_atomic_store(&slot[par*8 + idx], v, __ATOMIC_RELEASE, __HIP_MEMORY_SCOPE_AGENT);
      ull got;
      for (;;){
        got = (lane < 8) ? __hip_atomic_load(&slot[par*8 + lane], __ATOMIC_RELAXED, __HIP_MEMORY_SCOPE_AGENT) : 0;
        ull ok = __ballot(lane >= 8 || (int)(got >> 45) == phase);
        if (ok == ~0ull) break;
        __builtin_amdgcn_s_sleep(1);
      }
#pragma unroll
      for (int m = 1; m < 8; m <<= 1){
        ull o = (ull)__shfl_xor((long long)got, m, 64);
        if (o > got) got = o;
      }
      if (lane == 0) sCur = unpackI(got);
    }
    __syncthreads();
    cur = sCur;
  }
  __syncthreads();

  if (idx == 0){
    if (tid == 0){
      for (int i = 1; i < 16; i++){
        int key = selS[i]; int j = i - 1;
        while (j >= 0 && selS[j] > key){ selS[j+1] = selS[j]; j--; }
        selS[j+1] = key;
      }
    }
    __syncthreads();
    for (int idx2 = tid; idx2 < 1024; idx2 += 512)
      ws[tail + TT_SEL + bb*3072 + g*1024 + idx2] = pts[(size_t)selS[idx2 >> 6]*64 + (idx2 & 63)];
    __threadfence();
  }
  __syncthreads();
  if (tid == 0) atomicAdd(gcnt, 1);
  if (g != 0 || idx != 0) return;

  // ---- kG tail (per batch); wpec register-resident (spill-safe: P dead here)
  if (tid == 0){
    while (__hip_atomic_load(gcnt, __ATOMIC_RELAXED, __HIP_MEMORY_SCOPE_AGENT) < 24)
      __builtin_amdgcn_s_sleep(1);
    __threadfence();
  }
  __syncthreads();
  if (tid < 64){
    const float gw1 = ld(gWsa1, tid, bf);
    float wpec[64];
#pragma unroll
    for (int cn = 0; cn < 64; cn++) wpec[cn] = ld(gWpe, cn*64 + tid, bf);
    float lxs = lxsS[tid];
    float G = 0.f;
#pragma unroll
    for (int cn = 0; cn < 64; cn++) G += __shfl(lxs, cn, 64) * wpec[cn];
    GS[tid] = G;
    const float* selp = ws + tail + TT_SEL + bb*3072;
    for (int m = 0; m < 16; m++){
      float plx = selp[m*64 + tid];
      float g2 = 0.f;
#pragma unroll
      for (int cn = 0; cn < 64; cn++) g2 += __shfl(plx, cn, 64) * wpec[cn];
      gfS[m*64 + tid] = g2;
      float pkv = selp[1024 + m*64 + tid];
      float part = waveSum((pkv + g2) * gw1);
      if (tid == 0) betaS[m] = part;
    }
  }
  __syncthreads();
  if (tid < 64){
    float mx = -1e30f;
    for (int m = 0; m < 16; m++) mx = fmaxf(mx, -betaS[m]);
    float ssum = 0.f;
    for (int m = 0; m < 16; m++) ssum += expf(-betaS[m] - mx);
    float A = 0.f;
    for (int m = 0; m < 16; m++){
      float sg = expf(-betaS[m] - mx) / ssum;
      float pv = ws[tail + TT_SEL + bb*3072 + 2048 + m*64 + tid];
      float Sg = 8192.0f * (pv - gfS[m*64 + tid]) + GS[tid];
      A += sg * Sg;
    }
    float cg = 0.f;
#pragma unroll
    for (int cn = 0; cn < 64; cn++) cg += __shfl(A, cn, 64) * ld(gWsa2, cn*64 + tid, bf);
    ws[tail + TT_CG + bb*64 + tid] = cg;
  }
}

// ---- kZeroSpace: grid (2700,1,nb)
__global__ void kZeroSpace(float* __restrict__ ws, int offSp, int strSp, int bb0){
  const int bb = bb0 + blockIdx.z;
  float4 z = make_float4(0.f, 0.f, 0.f, 0.f);
  ((float4*)(ws + offSp + (size_t)bb*strSp))[blockIdx.x*256 + threadIdx.x] = z;
}

// ---- kImg: LN + GELU + scatter-add
__global__ void __launch_bounds__(256, 4) kImg(const void* __restrict__ ev,
    const void* __restrict__ lnw, const void* __restrict__ lnb,
    float* __restrict__ ws, int offB, int strB, int offSp, int strSp,
    int tail, int bb0){
  const bool bf = isbf(ev);
  const int bb = bb0 + blockIdx.z;
  const int lane = threadIdx.x & 63, w = threadIdx.x >> 6;
  const float cg = ws[tail + TT_CG + bb*64 + lane];
  const float lw = ld(lnw, lane, bf), lb = ld(lnb, lane, bf);
  float* space = ws + offSp + (size_t)bb*strSp;
  const float* Bp = ws + offB + (size_t)bb*strB;
#pragma unroll
  for (int i = 0; i < 2; i++){
    const int n = blockIdx.x*8 + w + 4*i;
    float x = Bp[n*64 + lane] + cg;
    float mu = waveSum(x) * (1.0f/64.0f);
    float dv = x - mu;
    float var = waveSum(dv*dv) * (1.0f/64.0f);
    float xn = dv / sqrtf(var + 1e-5f);
    float y = xn * lw + lb;
    float h = 0.5f * y * (1.0f + erff(y * 0.70710678118654752f));
    const int e4 = (bb*NB + n)*4;
    float exf = ld(ev, e4+0, bf), eyf = ld(ev, e4+1, bf), epf = ld(ev, e4+3, bf);
    int xi = (int)floorf(exf), yi = (int)floorf(eyf);
    int flat = yi*IMG_W + xi;
    flat = max(0, min(HWPIX-1, flat));
    atomicAdd(space + flat*64 + lane, epf * h);
  }
}

// ---- kStat: cnt,sum,sumsq per batch
__global__ void __launch_bounds__(256) kStat(float* __restrict__ ws,
    int offSp, int strSp, int tail, int bb0){
  const int bb = bb0 + blockIdx.z;
  const float4* sp = (const float4*)(ws + offSp + (size_t)bb*strSp);
  float cnt = 0.f, sum = 0.f, ssq = 0.f;
  for (unsigned i = blockIdx.x*256u + threadIdx.x; i < SPB/4; i += 65536u){
    float4 v = sp[i];
    if (v.x != 0.f){ cnt += 1.f; sum += v.x; ssq += v.x*v.x; }
    if (v.y != 0.f){ cnt += 1.f; sum += v.y; ssq += v.y*v.y; }
    if (v.z != 0.f){ cnt += 1.f; sum += v.z; ssq += v.z*v.z; }
    if (v.w != 0.f){ cnt += 1.f; sum += v.w; ssq += v.w*v.w; }
  }
  cnt = waveSum(cnt); sum = waveSum(sum); ssq = waveSum(ssq);
  __shared__ float rc[4], rs[4], rq[4];
  const int lane = threadIdx.x & 63, w = threadIdx.x >> 6;
  if (lane == 0){ rc[w] = cnt; rs[w] = sum; rq[w] = ssq; }
  __syncthreads();
  if (threadIdx.x == 0){
    atomicAdd(&ws[tail + TT_STATS + bb*16 + 0], rc[0]+rc[1]+rc[2]+rc[3]);
    atomicAdd(&ws[tail + TT_STATS + bb*16 + 1], rs[0]+rs[1]+rs[2]+rs[3]);
    atomicAdd(&ws[tail + TT_STATS + bb*16 + 2], rq[0]+rq[1]+rq[2]+rq[3]);
  }
}

// ---- kOut: LDS-transpose 64hw x 64c; var from sum/sumsq
__global__ void __launch_bounds__(256) kOut(const void* __restrict__ ev,
    const float* __restrict__ ws, void* __restrict__ out,
    int offSp, int strSp, int tail, int bb0){
  const bool bf = isbf(ev);
  const int bb = bb0 + blockIdx.z;
  __shared__ float tile[64*64];
  const int tid = threadIdx.x;
  const int hw0 = blockIdx.x*64;
  const float* sp = ws + offSp + (size_t)bb*strSp;
#pragma unroll
  for (int i = 0; i < 16; i++){
    int idx = tid + 256*i;
    tile[idx] = sp[(size_t)hw0*64 + idx];
  }
  const float cnt = ws[tail + TT_STATS + bb*16 + 0];
  const float sum = ws[tail + TT_STATS + bb*16 + 1];
  const float ssq = ws[tail + TT_STATS + bb*16 + 2];
  const float mean = sum / fmaxf(cnt, 1.f);
  const float m2   = fmaxf(ssq - sum*mean, 0.f);
  const float var  = m2 / fmaxf(cnt - 1.f, 1.f);
  const float stdv = sqrtf(var);
  __syncthreads();
  const int c = tid >> 2, sub = tid & 3;
#pragma unroll
  for (int j = 0; j < 16; j++){
    int hwl = sub*16 + j;
    float x = tile[hwl*64 + c];
    float centered = (x != 0.f) ? (x - mean) : x;
    float normed = (stdv > 0.f) ? (centered / stdv) : centered;
    float o = (cnt > 0.f) ? normed : x;
    stout(out, (long)(bb*64 + c)*HWPIX + hw0 + hwl, o, bf);
  }
}

extern "C" void kernel_launch(void* const* d_in, const int* in_sizes, int n_in,
                              void* d_out, int out_size, void* d_ws, size_t ws_size,
                              hipStream_t stream){
  (void)in_sizes; (void)n_in; (void)out_size;
  const void* ev     = d_in[0];
  const void* Wm     = d_in[1];
  const void* Wpe    = d_in[2];
  const void* lnw    = d_in[3];
  const void* lnb    = d_in[4];
  const void* lxWq   = d_in[5];
  const void* lxWk   = d_in[6];
  const void* lxWv   = d_in[7];
  const void* lxWsa1 = d_in[8];
  const void* lxWsa2 = d_in[9];
  // d_in[10] = gx_Wq : unused (cancels in n-independent softmax)
  const void* gxWk   = d_in[11];
  const void* gxWv   = d_in[12];
  const void* gxWpe  = d_in[13];
  const void* gxWsa1 = d_in[14];
  const void* gxWsa2 = d_in[15];
  float* ws = (float*)d_ws;

  // Parallel layout: B[2NC] | SPACE[2SPB] (aliases A,C,LXP) | tail
  const int P_TAIL = 2*NC + 2*SPB;
  const size_t PAR_BYTES = (size_t)(P_TAIL + TT_TOT) * 4;
  const bool par = ws_size >= PAR_BYTES;

  int offB, strB, offSp, strSp, offA, strA, offC, strC, offLXP, strLXP, tail;
  if (par){
    offB = 0;        strB = NC;
    offSp = 2*NC;    strSp = SPB;
    offA = 2*NC;     strA = NC;
    offC = 4*NC;     strC = NC;
    offLXP = 6*NC;   strLXP = 65536;
    tail = P_TAIL;
  } else {
    offSp = 0;       strSp = 0;
    offA = 0;        strA = 0;
    offC = NC;       strC = 0;
    offLXP = 2*NC;   strLXP = 0;
    offB = SPB;      strB = 0;
    tail = SPB + NC;
  }
  const int nb = par ? 2 : 1;
  const int iters = par ? 1 : 2;

  kW<<<1, 256, 0, stream>>>(ev, lxWq, lxWk, Wpe, lxWsa1, ws, tail);
  for (int t = 0; t < iters; t++){
    const int bb0 = par ? 0 : t;
    kE<<<dim3(8,1,nb), 256, 0, stream>>>(ev, ws, tail, bb0);
    kA<<<dim3(1024,1,nb), 256, 0, stream>>>(ev, Wm, Wpe, lxWv, ws, offA, strA, tail, bb0);
    kB<<<dim3(16,1,nb), 64, 0, stream>>>(ev, Wm, lxWv, lxWsa2, ws, tail, bb0);
    kC<<<dim3(1024,1,nb), 256, 0, stream>>>(ev, gxWk, gxWv, ws,
        offA, strA, offB, strB, offC, strC, offLXP, strLXP, tail, bb0);
    kL<<<dim3(1,1,nb), 512, 0, stream>>>(ws, offLXP, strLXP, tail, bb0);
    kFPS<<<dim3(8,3,nb), 512, 0, stream>>>(ev, gxWk, gxWv, gxWpe, gxWsa1, gxWsa2, ws,
        offA, strA, offB, strB, offC, strC, tail, bb0);
    kZeroSpace<<<dim3(2700,1,nb), 256, 0, stream>>>(ws, offSp, strSp, bb0);
    kImg<<<dim3(1024,1,nb), 256, 0, stream>>>(ev, lnw, lnb, ws, offB, strB, offSp, strSp, tail, bb0);
    kStat<<<dim3(256,1,nb), 256, 0, stream>>>(ws, offSp, strSp, tail, bb0);
    kOut<<<dim3(675,1,nb), 256, 0, stream>>>(ev, ws, d_out, offSp, strSp, tail, bb0);
  }
}

// Round 11
// 345.353 us; speedup vs baseline: 1.4070x; 1.2348x over previous
//
#include <hip/hip_runtime.h>

// EventTransformer on MI355X. B=2, N=8192, C=CN=64, M=16, H=180, W=240.
// fp32 internal in d_ws. I/O dtype (fp32/bf16) runtime-detected.
//
// R11: kC register-spill finally killed by moving gWk/gWv into LDS (32 KB/block;
// spill structurally impossible; 2-way LDS bank aliasing is free). R8/R10 showed
// per-thread wc[] arrays spill at VGPR=64 regardless of launch_bounds.

typedef unsigned short u16;
typedef unsigned long long ull;

#define NB 8192
#define IMG_H 180
#define IMG_W 240
#define HWPIX (IMG_H*IMG_W)          // 43200
#define SPB (HWPIX*64)               // 2,764,800 floats
#define NC (NB*64)                   // 524,288

// tail-relative offsets (floats), per-batch strides noted
#define TT_AC    0        // +bb*8192
#define TT_T     16384    // +bb*8192
#define TT_W1    32768
#define TT_EDGEV 32960    // +bb*1024
#define TT_EDGEF 35008    // +bb*1024
#define TT_S     37056    // +bb*1024  (holds SW = S@Wsa2)
#define TT_SEL   39104    // +bb*3072
#define TT_CG    45248    // +bb*64
#define TT_ESUM  45376    // +bb*16
#define TT_STATS 45408    // +bb*16
#define TT_SYNC  45440    // +(bb*3+g)*32 ; [par][blk] 2x8 ull
#define TT_GCNT  45632    // +bb*16
#define TT_LXS   45664    // +bb*64 (LXSUM, written whole by kL)
#define TT_ZOFF  45376
#define TT_ZCNT  288
#define TT_TOT   45792

__device__ __forceinline__ float bf2f(u16 u){
  union { unsigned int i; float f; } w; w.i = ((unsigned int)u) << 16; return w.f;
}
__device__ __forceinline__ u16 f2bf(float f){
  union { unsigned int i; float f; } w; w.f = f;
  unsigned int x = w.i;
  x += 0x7fffu + ((x >> 16) & 1u);   // RNE
  return (u16)(x >> 16);
}
__device__ __forceinline__ bool isbf(const void* ev){
  unsigned w3 = ((const unsigned*)ev)[3];
  return !(w3 == 0x3F800000u || w3 == 0xBF800000u);
}
__device__ __forceinline__ float ld(const void* p, int i, bool bf){
  return bf ? bf2f(((const u16*)p)[i]) : ((const float*)p)[i];
}
__device__ __forceinline__ void stout(void* o, long i, float v, bool bf){
  if (bf) ((u16*)o)[i] = f2bf(v); else ((float*)o)[i] = v;
}
__device__ __forceinline__ float waveSum(float v){
#pragma unroll
  for (int m = 1; m < 64; m <<= 1) v += __shfl_xor(v, m, 64);
  return v;
}
__device__ __forceinline__ ull waveMaxU64(ull v){
#pragma unroll
  for (int m = 1; m < 64; m <<= 1){
    ull o = (ull)__shfl_xor((long long)v, m, 64);
    if (o > v) v = o;
  }
  return v;
}
// pack: [52:45]=phase, [44:13]=dist bits (d>=0), [12:0]=8191-idx (tie->min idx)
__device__ __forceinline__ ull packPDI(int phase, float d, int n){
  return ((ull)phase << 45) | ((ull)__float_as_uint(d) << 13) | (ull)(8191 - n);
}
__device__ __forceinline__ int unpackI(ull p){ return 8191 - (int)(p & 0x1FFFull); }

// ---- kW: weight precompute + tail zero (runs once)
__global__ void kW(const void* __restrict__ ev, const void* __restrict__ Wq,
                   const void* __restrict__ Wk, const void* __restrict__ Wpe,
                   const void* __restrict__ w1, float* __restrict__ ws, int tail){
  const bool bf = isbf(ev);
  const int tid = threadIdx.x;  // 256
  for (int i = tid; i < TT_ZCNT; i += 256) ws[tail + TT_ZOFF + i] = 0.f;
  if (tid < 64){
    float s1 = 0.f, s2 = 0.f;
    for (int c = 0; c < 64; c++){
      float wc = ld(w1, c, bf);
      s1 += ld(Wq, tid*64 + c, bf) * wc;
      s2 += ld(Wk, tid*64 + c, bf) * wc;
    }
    ws[tail + TT_W1 + tid] = s1;
    ws[tail + TT_W1 + 64 + tid] = s2;
    if (tid < 4){
      float s3 = 0.f;
      for (int c = 0; c < 64; c++) s3 += ld(Wpe, tid*64 + c, bf) * ld(w1, c, bf);
      ws[tail + TT_W1 + 128 + tid] = s3;
    }
  }
}

// ---- kE: ESUM[bb][i] = sum_n events[bb,n,i]
__global__ void __launch_bounds__(256) kE(const void* __restrict__ ev,
    float* __restrict__ ws, int tail, int bb0){
  const bool bf = isbf(ev);
  const int bb = bb0 + blockIdx.z;
  const int lane = threadIdx.x & 63, w = threadIdx.x >> 6;
  float s0 = 0.f, s1 = 0.f, s2 = 0.f, s3 = 0.f;
#pragma unroll
  for (int j = 0; j < 4; j++){
    int r = blockIdx.x*256 + threadIdx.x + 2048*j;
    const int e4 = (bb*NB + r)*4;
    s0 += ld(ev, e4+0, bf); s1 += ld(ev, e4+1, bf);
    s2 += ld(ev, e4+2, bf); s3 += ld(ev, e4+3, bf);
  }
  s0 = waveSum(s0); s1 = waveSum(s1); s2 = waveSum(s2); s3 = waveSum(s3);
  __shared__ float r4[4][4];
  if (lane == 0){ r4[w][0]=s0; r4[w][1]=s1; r4[w][2]=s2; r4[w][3]=s3; }
  __syncthreads();
  if (threadIdx.x < 4)
    atomicAdd(&ws[tail + TT_ESUM + bb*16 + threadIdx.x],
              r4[0][threadIdx.x]+r4[1][threadIdx.x]+r4[2][threadIdx.x]+r4[3][threadIdx.x]);
}

// ---- kA: 1024 blocks/batch, 8 rows each. Spill-free.
__global__ void __launch_bounds__(256, 4) kA(const void* __restrict__ ev,
    const void* __restrict__ Wm, const void* __restrict__ Wpe,
    const void* __restrict__ Wv, float* __restrict__ ws,
    int offA, int strA, int tail, int bb0){
  const bool bf = isbf(ev);
  const int bb = bb0 + blockIdx.z;
  const int lane = threadIdx.x & 63, w = threadIdx.x >> 6;
  float* A = ws + offA + (size_t)bb*strA;
  const float wq1 = ws[tail + TT_W1 + lane];
  const float wk1 = ws[tail + TT_W1 + 64 + lane];
  const float wp10 = ws[tail+TT_W1+128], wp11 = ws[tail+TT_W1+129],
              wp12 = ws[tail+TT_W1+130], wp13 = ws[tail+TT_W1+131];
  const float wm0 = ld(Wm, 0*64+lane, bf), wm1 = ld(Wm, 1*64+lane, bf),
              wm2 = ld(Wm, 2*64+lane, bf), wm3 = ld(Wm, 3*64+lane, bf);
  const bool edgeBlk = (blockIdx.x == 0 || blockIdx.x == 1023);
#pragma unroll
  for (int i = 0; i < 2; i++){
    const int n = blockIdx.x*8 + w + 4*i;
    const int e4 = (bb*NB + n)*4;
    float e0 = ld(ev, e4+0, bf), e1 = ld(ev, e4+1, bf),
          e2 = ld(ev, e4+2, bf), e3 = ld(ev, e4+3, bf);
    float lx = e0*wm0 + e1*wm1 + e2*wm2 + e3*wm3;
    float epe = e0*wp10 + e1*wp11 + e2*wp12 + e3*wp13;
    float acv = waveSum(lx * wq1) + epe;
    float tv  = waveSum(lx * wk1) + epe;
    A[n*64 + lane] = lx;
    if (lane == 0){
      ws[tail + TT_AC + bb*8192 + n] = acv;
      ws[tail + TT_T  + bb*8192 + n] = tv;
    }
    if (edgeBlk && (n < 8 || n >= NB-8)){
      int e = (n < 8) ? n : (n - (NB-16));
      float v = 0.f;
      for (int cn = 0; cn < 64; cn++)
        v += __shfl(lx, cn, 64) * ld(Wv, cn*64 + lane, bf);
      float f = e0*ld(Wpe, lane, bf) + e1*ld(Wpe, 64+lane, bf)
              + e2*ld(Wpe, 128+lane, bf) + e3*ld(Wpe, 192+lane, bf);
      ws[tail + TT_EDGEV + bb*1024 + e*64 + lane] = v;
      ws[tail + TT_EDGEF + bb*1024 + e*64 + lane] = f;
    }
  }
}

// ---- kB: VSUM from ESUM algebra; S[m,c]; SW[m] = S[m]@Wsa2 (hoisted)
__global__ void __launch_bounds__(64) kB(const void* __restrict__ ev,
    const void* __restrict__ Wm, const void* __restrict__ Wv,
    const void* __restrict__ Wsa2, float* __restrict__ ws, int tail, int bb0){
  const bool bf = isbf(ev);
  const int bb = bb0 + blockIdx.z;
  const int m = blockIdx.x, lane = threadIdx.x;
  float tm = 0.f;
#pragma unroll
  for (int i = 0; i < 4; i++) tm += ws[tail + TT_ESUM + bb*16 + i] * ld(Wm, i*64 + lane, bf);
  float vs0 = 0.f, vs1 = 0.f;
#pragma unroll
  for (int j = 0; j < 64; j += 2){
    vs0 += __shfl(tm, j, 64)   * ld(Wv, j*64 + lane, bf);
    vs1 += __shfl(tm, j+1, 64) * ld(Wv, (j+1)*64 + lane, bf);
  }
  float vsum = vs0 + vs1;
  const int d = m - 8;
  float sv = 0.f, sf = 0.f;
  const float* EV = ws + tail + TT_EDGEV + bb*1024;
  const float* EF = ws + tail + TT_EDGEF + bb*1024;
  if (d < 0){
    for (int e = 16 + d; e < 16; e++){ sv += EV[e*64+lane]; sf += EF[e*64+lane]; }
  } else {
    for (int e = 0; e < d; e++){ sv += EV[e*64+lane]; sf += EF[e*64+lane]; }
  }
  float S = vsum - sv + sf;
  float sw0 = 0.f, sw1 = 0.f;
#pragma unroll
  for (int c = 0; c < 64; c += 2){
    sw0 += __shfl(S, c, 64)   * ld(Wsa2, c*64 + lane, bf);
    sw1 += __shfl(S, c+1, 64) * ld(Wsa2, (c+1)*64 + lane, bf);
  }
  ws[tail + TT_S + bb*1024 + m*64 + lane] = sw0 + sw1;
}

// ---- kC: softmax + lx_out (via SW) + kg/vg via LDS-resident weights + LXP
__global__ void __launch_bounds__(256) kC(const void* __restrict__ ev,
    const void* __restrict__ gWk, const void* __restrict__ gWv,
    float* __restrict__ ws,
    int offA, int strA, int offB, int strB, int offC, int strC,
    int offLXP, int strLXP, int tail, int bb0){
  const bool bf = isbf(ev);
  const int bb = bb0 + blockIdx.z;
  float* A = ws + offA + (size_t)bb*strA;
  float* Bp = ws + offB + (size_t)bb*strB;
  float* Cp = ws + offC + (size_t)bb*strC;
  __shared__ float SW_lds[1024];
  __shared__ float WK[4096];     // gWk in LDS (16 KB)
  __shared__ float WV[4096];     // gWv in LDS (16 KB)
  __shared__ float lred[4][64];
  const int tid = threadIdx.x, lane = tid & 63, w = tid >> 6;
  for (int i = tid; i < 1024; i += 256) SW_lds[i] = ws[tail + TT_S + bb*1024 + i];
  for (int i = tid; i < 4096; i += 256){
    WK[i] = ld(gWk, i, bf);
    WV[i] = ld(gWv, i, bf);
  }
  __syncthreads();
  float lxoR[2];
  float lxsum = 0.f;
#pragma unroll
  for (int i = 0; i < 2; i++){
    const int n = blockIdx.x*8 + w + 4*i;
    float lx  = A[n*64 + lane];
    float acn = ws[tail + TT_AC + bb*8192 + n];
    const int m = lane & 15;
    const int j = n + m - 8;
    float tv = (j >= 0 && j < NB) ? ws[tail + TT_T + bb*8192 + j] : 0.f;
    float logit = acn - tv;
    float mx = logit;
#pragma unroll
    for (int k = 1; k < 16; k <<= 1) mx = fmaxf(mx, __shfl_xor(mx, k, 64));
    float ex = expf(logit - mx);
    float sm = ex;
#pragma unroll
    for (int k = 1; k < 16; k <<= 1) sm += __shfl_xor(sm, k, 64);
    float sig = ex / sm;
    float sa = 0.f;
#pragma unroll
    for (int mm = 0; mm < 16; mm++) sa += __shfl(sig, mm, 64) * SW_lds[mm*64 + lane];
    float lxo = lx + sa;
    lxoR[i] = lxo;
    Bp[n*64 + lane] = lxo;
    lxsum += lxo;
  }
  lred[w][lane] = lxsum;
  // kg/vg: weights from LDS (2-way bank aliasing = free); shfl shared
#pragma unroll
  for (int i = 0; i < 2; i++){
    const int n = blockIdx.x*8 + w + 4*i;
    float k0 = 0.f, k1 = 0.f, v0 = 0.f, v1 = 0.f;
#pragma unroll
    for (int cn = 0; cn < 64; cn += 2){
      float x0 = __shfl(lxoR[i], cn, 64);
      float x1 = __shfl(lxoR[i], cn+1, 64);
      k0 += x0 * WK[cn*64 + lane];
      k1 += x1 * WK[(cn+1)*64 + lane];
      v0 += x0 * WV[cn*64 + lane];
      v1 += x1 * WV[(cn+1)*64 + lane];
    }
    A[n*64 + lane] = k0 + k1;
    Cp[n*64 + lane] = v0 + v1;
  }
  __syncthreads();
  if (tid < 64)
    ws[offLXP + (size_t)bb*strLXP + blockIdx.x*64 + tid] =
      lred[0][tid]+lred[1][tid]+lred[2][tid]+lred[3][tid];
}

// ---- kL: LXP (1024x64) -> LXSUM (64) per batch
__global__ void __launch_bounds__(512) kL(float* __restrict__ ws,
    int offLXP, int strLXP, int tail, int bb0){
  const int bb = bb0 + blockIdx.z;
  __shared__ float red[8][64];
  const int tid = threadIdx.x, c = tid & 63, grp = tid >> 6;
  const float* LXP = ws + offLXP + (size_t)bb*strLXP;
  float s = 0.f;
  for (int b2 = grp; b2 < 1024; b2 += 8) s += LXP[b2*64 + c];
  red[grp][c] = s;
  __syncthreads();
  if (tid < 64){
    float t = 0.f;
#pragma unroll
    for (int q = 0; q < 8; q++) t += red[q][tid];
    ws[tail + TT_LXS + bb*64 + tid] = t;
  }
}

// ---- kFPS: grid (8,3,nb). Leaderless slot barrier; kG tail on block (0,0).
__global__ void __launch_bounds__(512) kFPS(const void* __restrict__ ev,
    const void* __restrict__ gWk, const void* __restrict__ gWv,
    const void* __restrict__ gWpe, const void* __restrict__ gWsa1,
    const void* __restrict__ gWsa2, float* __restrict__ ws,
    int offA, int strA, int offB, int strB, int offC, int strC,
    int tail, int bb0){
  const int g = blockIdx.y, idx = blockIdx.x;
  const int bb = bb0 + blockIdx.z;
  const int tid = threadIdx.x, lane = tid & 63, w = tid >> 6;
  const float* pts = ws + (g == 0 ? offB + (size_t)bb*strB
                         : g == 1 ? offA + (size_t)bb*strA
                                  : offC + (size_t)bb*strC);
  ull* slot = (ull*)(ws + tail + TT_SYNC + (bb*3 + g)*32);  // [par*8+blk]
  int* gcnt = (int*)(ws + tail + TT_GCNT + bb*16);

  __shared__ float cent[64];
  __shared__ float lxsS[64];
  __shared__ ull   wvS[8];
  __shared__ int   selS[16];
  __shared__ int   sCur;
  __shared__ float gfS[1024];
  __shared__ float betaS[16];
  __shared__ float GS[64];

  const int n0 = idx*1024 + tid;       // +0 and +512
  float4 P[2][16];
#pragma unroll
  for (int j = 0; j < 2; j++)
#pragma unroll
    for (int i = 0; i < 16; i++)
      P[j][i] = ((const float4*)(pts + (size_t)(n0 + j*512)*64))[i];

  const bool bf = isbf(ev);
  // head: LXSUM precomputed by kL; cent analytically per group
  if (tid < 64){
    float lxs = ws[tail + TT_LXS + bb*64 + tid];
    lxsS[tid] = lxs;
    float c;
    if (g == 0) c = lxs * (1.0f/NB);
    else {
      const void* W = (g == 1) ? gWk : gWv;
      float s = 0.f;
#pragma unroll
      for (int j = 0; j < 64; j++) s += __shfl(lxs, j, 64) * ld(W, j*64 + tid, bf);
      c = s * (1.0f/NB);
    }
    cent[tid] = c;
  }
  __syncthreads();

  const float4* cv = (const float4*)cent;
  float md[2] = {1e10f, 1e10f};
  int cur;

  // phase 1: farthest0 (dist to bary, no md update)
  {
    float dd[2];
#pragma unroll
    for (int j = 0; j < 2; j++){
      float d = 0.f;
#pragma unroll
      for (int i = 0; i < 16; i++){
        float4 c = cv[i];
        float dx = P[j][i].x-c.x, dy = P[j][i].y-c.y, dz = P[j][i].z-c.z, dw = P[j][i].w-c.w;
        d += dx*dx; d += dy*dy; d += dz*dz; d += dw*dw;
      }
      dd[j] = d;
    }
    ull p0 = packPDI(1, dd[0], n0);
    ull p1 = packPDI(1, dd[1], n0 + 512);
    ull bp = waveMaxU64(p0 > p1 ? p0 : p1);
    if (lane == 0) wvS[w] = bp;
    __syncthreads();
    if (w == 0){
      ull v = (lane < 8) ? wvS[lane] : 0;
#pragma unroll
      for (int m = 1; m < 8; m <<= 1){
        ull o = (ull)__shfl_xor((long long)v, m, 64);
        if (o > v) v = o;
      }
      if (lane == 0)
        __hip_atomic_store(&slot[8 + idx], v, __ATOMIC_RELEASE, __HIP_MEMORY_SCOPE_AGENT);
      ull got;
      for (;;){
        got = (lane < 8) ? __hip_atomic_load(&slot[8 + lane], __ATOMIC_RELAXED, __HIP_MEMORY_SCOPE_AGENT) : 0;
        ull ok = __ballot(lane >= 8 || (int)(got >> 45) == 1);
        if (ok == ~0ull) break;
        __builtin_amdgcn_s_sleep(1);
      }
#pragma unroll
      for (int m = 1; m < 8; m <<= 1){
        ull o = (ull)__shfl_xor((long long)got, m, 64);
        if (o > got) got = o;
      }
      if (lane == 0) sCur = unpackI(got);
    }
    __syncthreads();
    cur = sCur;
  }

  for (int it = 0; ; it++){
    if (tid == 0) selS[it] = cur;
    if (it == 15) break;
    if (tid < 16) ((float4*)cent)[tid] = ((const float4*)(pts + (size_t)cur*64))[tid];
    __syncthreads();
    const int phase = it + 2;
    float dd[2];
#pragma unroll
    for (int j = 0; j < 2; j++){
      float d = 0.f;
#pragma unroll
      for (int i = 0; i < 16; i++){
        float4 c = cv[i];
        float dx = P[j][i].x-c.x, dy = P[j][i].y-c.y, dz = P[j][i].z-c.z, dw = P[j][i].w-c.w;
        d += dx*dx; d += dy*dy; d += dz*dz; d += dw*dw;
      }
      md[j] = fminf(md[j], d);
      dd[j] = md[j];
    }
    ull p0 = packPDI(phase, dd[0], n0);
    ull p1 = packPDI(phase, dd[1], n0 + 512);
    ull bp = waveMaxU64(p0 > p1 ? p0 : p1);
    if (lane == 0) wvS[w] = bp;
    __syncthreads();
    const int par = phase & 1;
    if (w == 0){
      ull v = (lane < 8) ? wvS[lane] : 0;
#pragma unroll
      for (int m = 1; m < 8; m <<= 1){
        ull o = (ull)__shfl_xor((long long)v, m, 64);
        if (o > v) v = o;
      }
      if (lane == 0)
        __hip_atomic_store(&slot[par*8 + idx], v, __ATOMIC_RELEASE, __HIP_MEMORY_SCOPE_AGENT);
      ull got;
      for (;;){
        got = (lane < 8) ? __hip_atomic_load(&slot[par*8 + lane], __ATOMIC_RELAXED, __HIP_MEMORY_SCOPE_AGENT) : 0;
        ull ok = __ballot(lane >= 8 || (int)(got >> 45) == phase);
        if (ok == ~0ull) break;
        __builtin_amdgcn_s_sleep(1);
      }
#pragma unroll
      for (int m = 1; m < 8; m <<= 1){
        ull o = (ull)__shfl_xor((long long)got, m, 64);
        if (o > got) got = o;
      }
      if (lane == 0) sCur = unpackI(got);
    }
    __syncthreads();
    cur = sCur;
  }
  __syncthreads();

  if (idx == 0){
    if (tid == 0){
      for (int i = 1; i < 16; i++){
        int key = selS[i]; int j = i - 1;
        while (j >= 0 && selS[j] > key){ selS[j+1] = selS[j]; j--; }
        selS[j+1] = key;
      }
    }
    __syncthreads();
    for (int idx2 = tid; idx2 < 1024; idx2 += 512)
      ws[tail + TT_SEL + bb*3072 + g*1024 + idx2] = pts[(size_t)selS[idx2 >> 6]*64 + (idx2 & 63)];
    __threadfence();
  }
  __syncthreads();
  if (tid == 0) atomicAdd(gcnt, 1);
  if (g != 0 || idx != 0) return;

  // ---- kG tail (per batch); wpec register-resident (P dead here)
  if (tid == 0){
    while (__hip_atomic_load(gcnt, __ATOMIC_RELAXED, __HIP_MEMORY_SCOPE_AGENT) < 24)
      __builtin_amdgcn_s_sleep(1);
    __threadfence();
  }
  __syncthreads();
  if (tid < 64){
    const float gw1 = ld(gWsa1, tid, bf);
    float wpec[64];
#pragma unroll
    for (int cn = 0; cn < 64; cn++) wpec[cn] = ld(gWpe, cn*64 + tid, bf);
    float lxs = lxsS[tid];
    float G = 0.f;
#pragma unroll
    for (int cn = 0; cn < 64; cn++) G += __shfl(lxs, cn, 64) * wpec[cn];
    GS[tid] = G;
    const float* selp = ws + tail + TT_SEL + bb*3072;
    for (int m = 0; m < 16; m++){
      float plx = selp[m*64 + tid];
      float g2 = 0.f;
#pragma unroll
      for (int cn = 0; cn < 64; cn++) g2 += __shfl(plx, cn, 64) * wpec[cn];
      gfS[m*64 + tid] = g2;
      float pkv = selp[1024 + m*64 + tid];
      float part = waveSum((pkv + g2) * gw1);
      if (tid == 0) betaS[m] = part;
    }
  }
  __syncthreads();
  if (tid < 64){
    float mx = -1e30f;
    for (int m = 0; m < 16; m++) mx = fmaxf(mx, -betaS[m]);
    float ssum = 0.f;
    for (int m = 0; m < 16; m++) ssum += expf(-betaS[m] - mx);
    float A = 0.f;
    for (int m = 0; m < 16; m++){
      float sg = expf(-betaS[m] - mx) / ssum;
      float pv = ws[tail + TT_SEL + bb*3072 + 2048 + m*64 + tid];
      float Sg = 8192.0f * (pv - gfS[m*64 + tid]) + GS[tid];
      A += sg * Sg;
    }
    float cg = 0.f;
#pragma unroll
    for (int cn = 0; cn < 64; cn++) cg += __shfl(A, cn, 64) * ld(gWsa2, cn*64 + tid, bf);
    ws[tail + TT_CG + bb*64 + tid] = cg;
  }
}

// ---- kZeroSpace: grid (2700,1,nb)
__global__ void kZeroSpace(float* __restrict__ ws, int offSp, int strSp, int bb0){
  const int bb = bb0 + blockIdx.z;
  float4 z = make_float4(0.f, 0.f, 0.f, 0.f);
  ((float4*)(ws + offSp + (size_t)bb*strSp))[blockIdx.x*256 + threadIdx.x] = z;
}

// ---- kImg: LN + GELU + scatter-add
__global__ void __launch_bounds__(256, 4) kImg(const void* __restrict__ ev,
    const void* __restrict__ lnw, const void* __restrict__ lnb,
    float* __restrict__ ws, int offB, int strB, int offSp, int strSp,
    int tail, int bb0){
  const bool bf = isbf(ev);
  const int bb = bb0 + blockIdx.z;
  const int lane = threadIdx.x & 63, w = threadIdx.x >> 6;
  const float cg = ws[tail + TT_CG + bb*64 + lane];
  const float lw = ld(lnw, lane, bf), lb = ld(lnb, lane, bf);
  float* space = ws + offSp + (size_t)bb*strSp;
  const float* Bp = ws + offB + (size_t)bb*strB;
#pragma unroll
  for (int i = 0; i < 2; i++){
    const int n = blockIdx.x*8 + w + 4*i;
    float x = Bp[n*64 + lane] + cg;
    float mu = waveSum(x) * (1.0f/64.0f);
    float dv = x - mu;
    float var = waveSum(dv*dv) * (1.0f/64.0f);
    float xn = dv / sqrtf(var + 1e-5f);
    float y = xn * lw + lb;
    float h = 0.5f * y * (1.0f + erff(y * 0.70710678118654752f));
    const int e4 = (bb*NB + n)*4;
    float exf = ld(ev, e4+0, bf), eyf = ld(ev, e4+1, bf), epf = ld(ev, e4+3, bf);
    int xi = (int)floorf(exf), yi = (int)floorf(eyf);
    int flat = yi*IMG_W + xi;
    flat = max(0, min(HWPIX-1, flat));
    atomicAdd(space + flat*64 + lane, epf * h);
  }
}

// ---- kStat: cnt,sum,sumsq per batch
__global__ void __launch_bounds__(256) kStat(float* __restrict__ ws,
    int offSp, int strSp, int tail, int bb0){
  const int bb = bb0 + blockIdx.z;
  const float4* sp = (const float4*)(ws + offSp + (size_t)bb*strSp);
  float cnt = 0.f, sum = 0.f, ssq = 0.f;
  for (unsigned i = blockIdx.x*256u + threadIdx.x; i < SPB/4; i += 65536u){
    float4 v = sp[i];
    if (v.x != 0.f){ cnt += 1.f; sum += v.x; ssq += v.x*v.x; }
    if (v.y != 0.f){ cnt += 1.f; sum += v.y; ssq += v.y*v.y; }
    if (v.z != 0.f){ cnt += 1.f; sum += v.z; ssq += v.z*v.z; }
    if (v.w != 0.f){ cnt += 1.f; sum += v.w; ssq += v.w*v.w; }
  }
  cnt = waveSum(cnt); sum = waveSum(sum); ssq = waveSum(ssq);
  __shared__ float rc[4], rs[4], rq[4];
  const int lane = threadIdx.x & 63, w = threadIdx.x >> 6;
  if (lane == 0){ rc[w] = cnt; rs[w] = sum; rq[w] = ssq; }
  __syncthreads();
  if (threadIdx.x == 0){
    atomicAdd(&ws[tail + TT_STATS + bb*16 + 0], rc[0]+rc[1]+rc[2]+rc[3]);
    atomicAdd(&ws[tail + TT_STATS + bb*16 + 1], rs[0]+rs[1]+rs[2]+rs[3]);
    atomicAdd(&ws[tail + TT_STATS + bb*16 + 2], rq[0]+rq[1]+rq[2]+rq[3]);
  }
}

// ---- kOut: LDS-transpose 64hw x 64c; var from sum/sumsq
__global__ void __launch_bounds__(256) kOut(const void* __restrict__ ev,
    const float* __restrict__ ws, void* __restrict__ out,
    int offSp, int strSp, int tail, int bb0){
  const bool bf = isbf(ev);
  const int bb = bb0 + blockIdx.z;
  __shared__ float tile[64*64];
  const int tid = threadIdx.x;
  const int hw0 = blockIdx.x*64;
  const float* sp = ws + offSp + (size_t)bb*strSp;
#pragma unroll
  for (int i = 0; i < 16; i++){
    int idx = tid + 256*i;
    tile[idx] = sp[(size_t)hw0*64 + idx];
  }
  const float cnt = ws[tail + TT_STATS + bb*16 + 0];
  const float sum = ws[tail + TT_STATS + bb*16 + 1];
  const float ssq = ws[tail + TT_STATS + bb*16 + 2];
  const float mean = sum / fmaxf(cnt, 1.f);
  const float m2   = fmaxf(ssq - sum*mean, 0.f);
  const float var  = m2 / fmaxf(cnt - 1.f, 1.f);
  const float stdv = sqrtf(var);
  __syncthreads();
  const int c = tid >> 2, sub = tid & 3;
#pragma unroll
  for (int j = 0; j < 16; j++){
    int hwl = sub*16 + j;
    float x = tile[hwl*64 + c];
    float centered = (x != 0.f) ? (x - mean) : x;
    float normed = (stdv > 0.f) ? (centered / stdv) : centered;
    float o = (cnt > 0.f) ? normed : x;
    stout(out, (long)(bb*64 + c)*HWPIX + hw0 + hwl, o, bf);
  }
}

extern "C" void kernel_launch(void* const* d_in, const int* in_sizes, int n_in,
                              void* d_out, int out_size, void* d_ws, size_t ws_size,
                              hipStream_t stream){
  (void)in_sizes; (void)n_in; (void)out_size;
  const void* ev     = d_in[0];
  const void* Wm     = d_in[1];
  const void* Wpe    = d_in[2];
  const void* lnw    = d_in[3];
  const void* lnb    = d_in[4];
  const void* lxWq   = d_in[5];
  const void* lxWk   = d_in[6];
  const void* lxWv   = d_in[7];
  const void* lxWsa1 = d_in[8];
  const void* lxWsa2 = d_in[9];
  // d_in[10] = gx_Wq : unused (cancels in n-independent softmax)
  const void* gxWk   = d_in[11];
  const void* gxWv   = d_in[12];
  const void* gxWpe  = d_in[13];
  const void* gxWsa1 = d_in[14];
  const void* gxWsa2 = d_in[15];
  float* ws = (float*)d_ws;

  // Parallel layout: B[2NC] | SPACE[2SPB] (aliases A,C,LXP) | tail
  const int P_TAIL = 2*NC + 2*SPB;
  const size_t PAR_BYTES = (size_t)(P_TAIL + TT_TOT) * 4;
  const bool par = ws_size >= PAR_BYTES;

  int offB, strB, offSp, strSp, offA, strA, offC, strC, offLXP, strLXP, tail;
  if (par){
    offB = 0;        strB = NC;
    offSp = 2*NC;    strSp = SPB;
    offA = 2*NC;     strA = NC;
    offC = 4*NC;     strC = NC;
    offLXP = 6*NC;   strLXP = 65536;
    tail = P_TAIL;
  } else {
    offSp = 0;       strSp = 0;
    offA = 0;        strA = 0;
    offC = NC;       strC = 0;
    offLXP = 2*NC;   strLXP = 0;
    offB = SPB;      strB = 0;
    tail = SPB + NC;
  }
  const int nb = par ? 2 : 1;
  const int iters = par ? 1 : 2;

  kW<<<1, 256, 0, stream>>>(ev, lxWq, lxWk, Wpe, lxWsa1, ws, tail);
  for (int t = 0; t < iters; t++){
    const int bb0 = par ? 0 : t;
    kE<<<dim3(8,1,nb), 256, 0, stream>>>(ev, ws, tail, bb0);
    kA<<<dim3(1024,1,nb), 256, 0, stream>>>(ev, Wm, Wpe, lxWv, ws, offA, strA, tail, bb0);
    kB<<<dim3(16,1,nb), 64, 0, stream>>>(ev, Wm, lxWv, lxWsa2, ws, tail, bb0);
    kC<<<dim3(1024,1,nb), 256, 0, stream>>>(ev, gxWk, gxWv, ws,
        offA, strA, offB, strB, offC, strC, offLXP, strLXP, tail, bb0);
    kL<<<dim3(1,1,nb), 512, 0, stream>>>(ws, offLXP, strLXP, tail, bb0);
    kFPS<<<dim3(8,3,nb), 512, 0, stream>>>(ev, gxWk, gxWv, gxWpe, gxWsa1, gxWsa2, ws,
        offA, strA, offB, strB, offC, strC, tail, bb0);
    kZeroSpace<<<dim3(2700,1,nb), 256, 0, stream>>>(ws, offSp, strSp, bb0);
    kImg<<<dim3(1024,1,nb), 256, 0, stream>>>(ev, lnw, lnb, ws, offB, strB, offSp, strSp, tail, bb0);
    kStat<<<dim3(256,1,nb), 256, 0, stream>>>(ws, offSp, strSp, tail, bb0);
    kOut<<<dim3(675,1,nb), 256, 0, stream>>>(ev, ws, d_out, offSp, strSp, tail, bb0);
  }
}